// Round 8
// baseline (170.258 us; speedup 1.0000x reference)
//
#include <hip/hip_runtime.h>
#include <math.h>

typedef float f32x2 __attribute__((ext_vector_type(2)));

#define TW 64
#define TH 32
#define XH 74        // TW + 10 halo columns
#define NT 256
#define SSIM_C1 1e-4f
#define SSIM_C2 9e-4f

// r7 structure + bf16 vc intermediate (y-pairs packed in u32) -> 25.6 KB LDS
// -> 6 blocks/CU. Quantization point proven safe by round-5 bisect (bf16 T).
template <bool ATOMIC>
__global__ __launch_bounds__(NT, 6) void ssim_pk2(
    const float* __restrict__ img1, const float* __restrict__ img2,
    const float* __restrict__ window, float* __restrict__ partials)
{
    __shared__ unsigned vc[5][16][80];   // [field][ypair][xh] lo=even row, hi=odd
    __shared__ float wred[4];

    const int tid = threadIdx.x;
    const int x0 = blockIdx.x * TW;
    const int y0 = blockIdx.y * TH;
    const float* p1 = img1 + (size_t)blockIdx.z * (512 * 512);
    const float* p2 = img2 + (size_t)blockIdx.z * (512 * 512);

    // 1D gaussian from window row 5 (w2[5][j] = g5*g[j], w2[5][5] = g5^2)
    float g[11];
    {
        float r5 = rsqrtf(window[60]);
        #pragma unroll
        for (int j = 0; j < 11; ++j) g[j] = window[55 + j] * r5;
    }
    // pair table: gp[t] = (g[t], g[t-1]), zero-padded at the ends
    f32x2 gp[12];
    gp[0] = (f32x2){g[0], 0.f};
    #pragma unroll
    for (int t = 1; t < 11; ++t) gp[t] = (f32x2){g[t], g[t - 1]};
    gp[11] = (f32x2){0.f, g[10]};

    // ---- pass 1: vertical conv (74 cols x 4 y-octets = 296 tasks) ----
    for (int l = tid; l < XH * (TH / 8); l += NT) {
        int xh = l % XH;
        int yq = l / XH;
        int gx = x0 - 5 + xh;
        int yb = y0 + yq * 8;
        bool xok = (unsigned)gx < 512u;

        float ra[18], rb[18];
        #pragma unroll
        for (int j = 0; j < 18; ++j) {
            int gy = yb - 5 + j;
            float a = 0.f, b = 0.f;
            if (xok && (unsigned)gy < 512u) {
                int idx = gy * 512 + gx;
                a = p1[idx];
                b = p2[idx];
            }
            ra[j] = a; rb[j] = b;
        }

        f32x2 acc[5][4];
        #pragma unroll
        for (int f = 0; f < 5; ++f)
            #pragma unroll
            for (int i2 = 0; i2 < 4; ++i2) acc[f][i2] = (f32x2){0.f, 0.f};

        #pragma unroll
        for (int j = 0; j < 18; ++j) {
            float a = ra[j], b = rb[j];
            float aa = a * a, bb = b * b, ab = a * b;
            #pragma unroll
            for (int i2 = 0; i2 < 4; ++i2) {
                int t = j - 2 * i2;
                if (t >= 0 && t < 12) {
                    f32x2 w = gp[t];
                    acc[0][i2] += w * a;
                    acc[1][i2] += w * b;
                    acc[2][i2] += w * aa;
                    acc[3][i2] += w * bb;
                    acc[4][i2] += w * ab;
                }
            }
        }
        int ypb = yq * 4;   // ypair base
        #pragma unroll
        for (int f = 0; f < 5; ++f)
            #pragma unroll
            for (int i2 = 0; i2 < 4; ++i2) {
                unsigned pk;
                asm("v_cvt_pk_bf16_f32 %0, %1, %2"
                    : "=v"(pk) : "v"(acc[f][i2].x), "v"(acc[f][i2].y));
                vc[f][ypb + i2][xh] = pk;
            }
    }
    __syncthreads();

    // ---- pass 2: horizontal conv + SSIM ----
    // thread owns y-pair (yp) x 4 outputs (x4..x4+3): both bf16 halves used.
    float lsum = 0.f;
    {
        int x4 = (tid & 15) * 4;
        int yp = tid >> 4;
        f32x2 m[5][2][2];   // [field][row][xpair]
        #pragma unroll
        for (int f = 0; f < 5; ++f) {
            const unsigned* row = &vc[f][yp][x4];
            uint4 q0 = *(const uint4*)(row);
            uint4 q1 = *(const uint4*)(row + 4);
            uint4 q2 = *(const uint4*)(row + 8);
            uint4 q3 = *(const uint4*)(row + 12);
            unsigned u[16] = {q0.x,q0.y,q0.z,q0.w, q1.x,q1.y,q1.z,q1.w,
                              q2.x,q2.y,q2.z,q2.w, q3.x,q3.y,q3.z,q3.w};
            f32x2 a0[2] = {(f32x2){0.f,0.f}, (f32x2){0.f,0.f}};
            f32x2 a1[2] = {(f32x2){0.f,0.f}, (f32x2){0.f,0.f}};
            #pragma unroll
            for (int j = 0; j < 15; ++j) {
                float v0 = __uint_as_float(u[j] << 16);          // even row
                float v1 = __uint_as_float(u[j] & 0xFFFF0000u);  // odd row
                #pragma unroll
                for (int i2 = 0; i2 < 2; ++i2) {
                    int t = j - 2 * i2;
                    if (t >= 0 && t < 12) {
                        f32x2 w = gp[t];
                        a0[i2] += w * v0;
                        a1[i2] += w * v1;
                    }
                }
            }
            m[f][0][0] = a0[0]; m[f][0][1] = a0[1];
            m[f][1][0] = a1[0]; m[f][1][1] = a1[1];
        }
        #pragma unroll
        for (int r = 0; r < 2; ++r)
            #pragma unroll
            for (int i2 = 0; i2 < 2; ++i2) {
                f32x2 mu1 = m[0][r][i2], mu2 = m[1][r][i2];
                f32x2 m11 = mu1 * mu1, m22 = mu2 * mu2, m12 = mu1 * mu2;
                f32x2 s1 = m[2][r][i2] - m11;
                f32x2 s2 = m[3][r][i2] - m22;
                f32x2 s12 = m[4][r][i2] - m12;
                f32x2 num = (2.f * m12 + SSIM_C1) * (2.f * s12 + SSIM_C2);
                f32x2 den = (m11 + m22 + SSIM_C1) * (s1 + s2 + SSIM_C2);
                float v0 = num.x * __builtin_amdgcn_rcpf(den.x);
                float v1 = num.y * __builtin_amdgcn_rcpf(den.y);
                lsum += fminf(fmaxf(v0, 0.f), 1.f);
                lsum += fminf(fmaxf(v1, 0.f), 1.f);
            }
    }

    // ---- block reduce ----
    #pragma unroll
    for (int off = 32; off > 0; off >>= 1) lsum += __shfl_down(lsum, off);
    if ((tid & 63) == 0) wred[tid >> 6] = lsum;
    __syncthreads();
    if (tid == 0) {
        float bsum = wred[0] + wred[1] + wred[2] + wred[3];
        int bid = (blockIdx.z * gridDim.y + blockIdx.y) * gridDim.x + blockIdx.x;
        if (ATOMIC) atomicAdd(&partials[0], bsum);
        else        partials[bid] = bsum;
    }
}

__global__ void ssim_finalize(const float* __restrict__ partials, int n,
                              float* __restrict__ out, float inv_npx)
{
    __shared__ float w[4];
    float s = 0.f;
    for (int i = threadIdx.x; i < n; i += 256) s += partials[i];
    #pragma unroll
    for (int off = 32; off > 0; off >>= 1) s += __shfl_down(s, off);
    if ((threadIdx.x & 63) == 0) w[threadIdx.x >> 6] = s;
    __syncthreads();
    if (threadIdx.x == 0) {
        float total = w[0] + w[1] + w[2] + w[3];
        float loss = 1.0f - total * inv_npx;
        out[0] = fmaxf(loss, 0.0f);
    }
}

extern "C" void kernel_launch(void* const* d_in, const int* in_sizes, int n_in,
                              void* d_out, int out_size, void* d_ws, size_t ws_size,
                              hipStream_t stream) {
    const float* img1   = (const float*)d_in[0];
    const float* img2   = (const float*)d_in[1];
    const float* window = (const float*)d_in[2];
    float* out      = (float*)d_out;
    float* partials = (float*)d_ws;

    int planes = in_sizes[0] >> 18;          // 48
    dim3 grid(512 / TW, 512 / TH, planes);   // 8 x 16 x 48 = 6144 blocks
    int npart = grid.x * grid.y * grid.z;
    float inv_npx = 1.0f / (float)in_sizes[0];

    if (ws_size >= (size_t)npart * sizeof(float)) {
        ssim_pk2<false><<<grid, NT, 0, stream>>>(img1, img2, window, partials);
        ssim_finalize<<<1, 256, 0, stream>>>(partials, npart, out, inv_npx);
    } else {
        hipMemsetAsync(d_ws, 0, sizeof(float), stream);
        ssim_pk2<true><<<grid, NT, 0, stream>>>(img1, img2, window, partials);
        ssim_finalize<<<1, 256, 0, stream>>>(partials, 1, out, inv_npx);
    }
}

// Round 9
// 68.187 us; speedup vs baseline: 2.4969x; 2.4969x over previous
//
#include <hip/hip_runtime.h>
#include <math.h>

typedef float f32x2 __attribute__((ext_vector_type(2)));

#define TW 64
#define TH 32
#define XH 74        // TW + 10 halo columns
#define NT 256
#define SSIM_C1 1e-4f
#define SSIM_C2 9e-4f

// r8 structure (bf16 vc, 25.6 KB LDS -> 6 blocks/CU by LDS) with the spill
// fixed: launch_bounds(256,4) caps VGPR at 128 (compiler needs ~68, no spill).
// r8's (256,6) forced VGPR=40 -> scratch spills -> 372MB FETCH / 319MB WRITE.
template <bool ATOMIC>
__global__ __launch_bounds__(NT, 4) void ssim_pk3(
    const float* __restrict__ img1, const float* __restrict__ img2,
    const float* __restrict__ window, float* __restrict__ partials)
{
    __shared__ unsigned vc[5][16][80];   // [field][ypair][xh] lo=even row, hi=odd
    __shared__ float wred[4];

    const int tid = threadIdx.x;
    const int x0 = blockIdx.x * TW;
    const int y0 = blockIdx.y * TH;
    const float* p1 = img1 + (size_t)blockIdx.z * (512 * 512);
    const float* p2 = img2 + (size_t)blockIdx.z * (512 * 512);

    // 1D gaussian from window row 5 (w2[5][j] = g5*g[j], w2[5][5] = g5^2)
    float g[11];
    {
        float r5 = rsqrtf(window[60]);
        #pragma unroll
        for (int j = 0; j < 11; ++j) g[j] = window[55 + j] * r5;
    }
    // pair table: gp[t] = (g[t], g[t-1]), zero-padded at the ends
    f32x2 gp[12];
    gp[0] = (f32x2){g[0], 0.f};
    #pragma unroll
    for (int t = 1; t < 11; ++t) gp[t] = (f32x2){g[t], g[t - 1]};
    gp[11] = (f32x2){0.f, g[10]};

    // ---- pass 1: vertical conv (74 cols x 4 y-octets = 296 tasks) ----
    for (int l = tid; l < XH * (TH / 8); l += NT) {
        int xh = l % XH;
        int yq = l / XH;
        int gx = x0 - 5 + xh;
        int yb = y0 + yq * 8;
        bool xok = (unsigned)gx < 512u;

        float ra[18], rb[18];
        #pragma unroll
        for (int j = 0; j < 18; ++j) {
            int gy = yb - 5 + j;
            float a = 0.f, b = 0.f;
            if (xok && (unsigned)gy < 512u) {
                int idx = gy * 512 + gx;
                a = p1[idx];
                b = p2[idx];
            }
            ra[j] = a; rb[j] = b;
        }

        f32x2 acc[5][4];
        #pragma unroll
        for (int f = 0; f < 5; ++f)
            #pragma unroll
            for (int i2 = 0; i2 < 4; ++i2) acc[f][i2] = (f32x2){0.f, 0.f};

        #pragma unroll
        for (int j = 0; j < 18; ++j) {
            float a = ra[j], b = rb[j];
            float aa = a * a, bb = b * b, ab = a * b;
            #pragma unroll
            for (int i2 = 0; i2 < 4; ++i2) {
                int t = j - 2 * i2;
                if (t >= 0 && t < 12) {
                    f32x2 w = gp[t];
                    acc[0][i2] += w * a;
                    acc[1][i2] += w * b;
                    acc[2][i2] += w * aa;
                    acc[3][i2] += w * bb;
                    acc[4][i2] += w * ab;
                }
            }
        }
        int ypb = yq * 4;   // ypair base
        #pragma unroll
        for (int f = 0; f < 5; ++f)
            #pragma unroll
            for (int i2 = 0; i2 < 4; ++i2) {
                unsigned pk;
                asm("v_cvt_pk_bf16_f32 %0, %1, %2"
                    : "=v"(pk) : "v"(acc[f][i2].x), "v"(acc[f][i2].y));
                vc[f][ypb + i2][xh] = pk;
            }
    }
    __syncthreads();

    // ---- pass 2: horizontal conv + SSIM ----
    // thread owns y-pair (yp) x 4 outputs (x4..x4+3): both bf16 halves used.
    float lsum = 0.f;
    {
        int x4 = (tid & 15) * 4;
        int yp = tid >> 4;
        f32x2 m[5][2][2];   // [field][row][xpair]
        #pragma unroll
        for (int f = 0; f < 5; ++f) {
            const unsigned* row = &vc[f][yp][x4];
            uint4 q0 = *(const uint4*)(row);
            uint4 q1 = *(const uint4*)(row + 4);
            uint4 q2 = *(const uint4*)(row + 8);
            uint4 q3 = *(const uint4*)(row + 12);
            unsigned u[16] = {q0.x,q0.y,q0.z,q0.w, q1.x,q1.y,q1.z,q1.w,
                              q2.x,q2.y,q2.z,q2.w, q3.x,q3.y,q3.z,q3.w};
            f32x2 a0[2] = {(f32x2){0.f,0.f}, (f32x2){0.f,0.f}};
            f32x2 a1[2] = {(f32x2){0.f,0.f}, (f32x2){0.f,0.f}};
            #pragma unroll
            for (int j = 0; j < 15; ++j) {
                float v0 = __uint_as_float(u[j] << 16);          // even row
                float v1 = __uint_as_float(u[j] & 0xFFFF0000u);  // odd row
                #pragma unroll
                for (int i2 = 0; i2 < 2; ++i2) {
                    int t = j - 2 * i2;
                    if (t >= 0 && t < 12) {
                        f32x2 w = gp[t];
                        a0[i2] += w * v0;
                        a1[i2] += w * v1;
                    }
                }
            }
            m[f][0][0] = a0[0]; m[f][0][1] = a0[1];
            m[f][1][0] = a1[0]; m[f][1][1] = a1[1];
        }
        #pragma unroll
        for (int r = 0; r < 2; ++r)
            #pragma unroll
            for (int i2 = 0; i2 < 2; ++i2) {
                f32x2 mu1 = m[0][r][i2], mu2 = m[1][r][i2];
                f32x2 m11 = mu1 * mu1, m22 = mu2 * mu2, m12 = mu1 * mu2;
                f32x2 s1 = m[2][r][i2] - m11;
                f32x2 s2 = m[3][r][i2] - m22;
                f32x2 s12 = m[4][r][i2] - m12;
                f32x2 num = (2.f * m12 + SSIM_C1) * (2.f * s12 + SSIM_C2);
                f32x2 den = (m11 + m22 + SSIM_C1) * (s1 + s2 + SSIM_C2);
                float v0 = num.x * __builtin_amdgcn_rcpf(den.x);
                float v1 = num.y * __builtin_amdgcn_rcpf(den.y);
                lsum += fminf(fmaxf(v0, 0.f), 1.f);
                lsum += fminf(fmaxf(v1, 0.f), 1.f);
            }
    }

    // ---- block reduce ----
    #pragma unroll
    for (int off = 32; off > 0; off >>= 1) lsum += __shfl_down(lsum, off);
    if ((tid & 63) == 0) wred[tid >> 6] = lsum;
    __syncthreads();
    if (tid == 0) {
        float bsum = wred[0] + wred[1] + wred[2] + wred[3];
        int bid = (blockIdx.z * gridDim.y + blockIdx.y) * gridDim.x + blockIdx.x;
        if (ATOMIC) atomicAdd(&partials[0], bsum);
        else        partials[bid] = bsum;
    }
}

__global__ void ssim_finalize(const float* __restrict__ partials, int n,
                              float* __restrict__ out, float inv_npx)
{
    __shared__ float w[4];
    float s = 0.f;
    for (int i = threadIdx.x; i < n; i += 256) s += partials[i];
    #pragma unroll
    for (int off = 32; off > 0; off >>= 1) s += __shfl_down(s, off);
    if ((threadIdx.x & 63) == 0) w[threadIdx.x >> 6] = s;
    __syncthreads();
    if (threadIdx.x == 0) {
        float total = w[0] + w[1] + w[2] + w[3];
        float loss = 1.0f - total * inv_npx;
        out[0] = fmaxf(loss, 0.0f);
    }
}

extern "C" void kernel_launch(void* const* d_in, const int* in_sizes, int n_in,
                              void* d_out, int out_size, void* d_ws, size_t ws_size,
                              hipStream_t stream) {
    const float* img1   = (const float*)d_in[0];
    const float* img2   = (const float*)d_in[1];
    const float* window = (const float*)d_in[2];
    float* out      = (float*)d_out;
    float* partials = (float*)d_ws;

    int planes = in_sizes[0] >> 18;          // 48
    dim3 grid(512 / TW, 512 / TH, planes);   // 8 x 16 x 48 = 6144 blocks
    int npart = grid.x * grid.y * grid.z;
    float inv_npx = 1.0f / (float)in_sizes[0];

    if (ws_size >= (size_t)npart * sizeof(float)) {
        ssim_pk3<false><<<grid, NT, 0, stream>>>(img1, img2, window, partials);
        ssim_finalize<<<1, 256, 0, stream>>>(partials, npart, out, inv_npx);
    } else {
        hipMemsetAsync(d_ws, 0, sizeof(float), stream);
        ssim_pk3<true><<<grid, NT, 0, stream>>>(img1, img2, window, partials);
        ssim_finalize<<<1, 256, 0, stream>>>(partials, 1, out, inv_npx);
    }
}

// Round 10
// 51.070 us; speedup vs baseline: 3.3338x; 1.3352x over previous
//
#include <hip/hip_runtime.h>
#include <math.h>

typedef short bf16x8 __attribute__((ext_vector_type(8)));
typedef float f32x4 __attribute__((ext_vector_type(4)));
typedef unsigned short u16;

#define NT 256
#define C1c 1e-4f
#define C2c 9e-4f

// f32 -> bf16 round-to-nearest-even (non-negative, finite inputs)
__device__ inline u16 f2bf(float f) {
    unsigned u = __float_as_uint(f);
    return (u16)((u + 0x7FFFu + ((u >> 16) & 1u)) >> 16);
}
__device__ inline float bf2f(u16 h) { return __uint_as_float((unsigned)h << 16); }

// bijective rotation swizzle within a 48-col row; 4/8-aligned blocks never straddle
__device__ inline int rot48(int c, int x) {
    int cc = c + 8 * (x & 7);
    if (cc >= 48) cc -= 48;
    if (cc >= 48) cc -= 48;
    return cc;
}

// 64x32 output tile. Pass-1: per-lane A-frags built straight from global f32
// (2x float4 per img), products in f32, ONE cvt_pk rounding, 5 MFMAs vs wB
// (banded Toeplitz), C -> T[f][x][yhalo48] bf16 (r6-proven store).
// Pass-2: r5-proven MFMA (wA x T) + SSIM epilogue. All five fields cross
// identical rounding points with identical bf16 weights -> bias cancellation
// in s1/s2/s12.
template <bool ATOMIC>
__global__ __launch_bounds__(NT) void ssim_mfma2(
    const float* __restrict__ img1, const float* __restrict__ img2,
    const float* __restrict__ window, float* __restrict__ partials)
{
    __shared__ alignas(16) u16 T[5][64 * 48];   // [field][x][yhalo], rot48-swizzled
    __shared__ u16 wtab[64];                    // bf16 g at slots 20..30, zeros else
    __shared__ float wred[4];

    const int tid = threadIdx.x;
    const int x0 = blockIdx.x * 64;
    const int y0 = blockIdx.y * 32;
    const float* p1 = img1 + (size_t)blockIdx.z * (512 * 512);
    const float* p2 = img2 + (size_t)blockIdx.z * (512 * 512);

    // ---- weight table: zeros + error-feedback bf16 quantization of g ----
    if (tid < 64 && (tid < 20 || tid > 30)) wtab[tid] = 0;
    if (tid == 0) {
        float inv = 1.0f / sqrtf(window[60]);      // w2[5][5] = g5^2
        float carry = 0.f;
        for (int k = 0; k < 11; ++k) {
            float gk = window[55 + k] * inv + carry;
            u16 q = f2bf(gk);
            carry = gk - bf2f(q);
            wtab[20 + k] = q;
        }
    }
    __syncthreads();

    const int lane = tid & 63;
    const int lrow = lane & 15;
    const int lgrp = lane >> 4;
    const int wid = tid >> 6;

    // Toeplitz weight fragments (k = 8*lgrp + j; k-order cancels between frags)
    bf16x8 wB, wA;
    #pragma unroll
    for (int j = 0; j < 8; ++j) {
        int k = lgrp * 8 + j;
        wB[j] = (short)wtab[17 + k - lrow];   // pass1: g[k - n - 3]
        wA[j] = (short)wtab[20 + k - lrow];   // pass2: g[k - i]
    }
    f32x4 z4 = {0.f, 0.f, 0.f, 0.f};

    // interior: all pass-1 loads in-bounds (gx in [x0-8,x0+71], gy in [y0-5,y0+42])
    const bool interior = (x0 >= 8) && (x0 <= 440) && (y0 >= 5) && (y0 <= 469);

    // ---- pass 1: 12 positions (3 ry-tiles x 4 x-tiles), wave w owns n1=w ----
    for (int p = wid; p < 12; p += 4) {
        int m1 = p >> 2;
        int n1 = wid;
        int gy = y0 - 5 + 16 * m1 + lrow;
        int gxb = x0 - 8 + 16 * n1 + 8 * lgrp;

        float4 A0 = make_float4(0.f,0.f,0.f,0.f), A1 = A0, B0 = A0, B1 = A0;
        if (interior) {
            const float* r1 = p1 + gy * 512 + gxb;
            const float* r2 = p2 + gy * 512 + gxb;
            A0 = *(const float4*)(r1);
            A1 = *(const float4*)(r1 + 4);
            B0 = *(const float4*)(r2);
            B1 = *(const float4*)(r2 + 4);
        } else {
            bool yok = (unsigned)gy < 512u;
            if (yok && gxb >= 0 && gxb <= 508) {
                A0 = *(const float4*)(p1 + gy * 512 + gxb);
                B0 = *(const float4*)(p2 + gy * 512 + gxb);
            }
            int gxb4 = gxb + 4;
            if (yok && gxb4 >= 0 && gxb4 <= 508) {
                A1 = *(const float4*)(p1 + gy * 512 + gxb4);
                B1 = *(const float4*)(p2 + gy * 512 + gxb4);
            }
        }
        float xa[8] = {A0.x, A0.y, A0.z, A0.w, A1.x, A1.y, A1.z, A1.w};
        float xb[8] = {B0.x, B0.y, B0.z, B0.w, B1.x, B1.y, B1.z, B1.w};

        unsigned ua[4], ub[4], uaa[4], ubb[4], uab[4];
        #pragma unroll
        for (int w = 0; w < 4; ++w) {
            float pa = xa[2*w], pb = xa[2*w+1];
            float qa = xb[2*w], qb = xb[2*w+1];
            asm("v_cvt_pk_bf16_f32 %0, %1, %2" : "=v"(ua[w])  : "v"(pa),      "v"(pb));
            asm("v_cvt_pk_bf16_f32 %0, %1, %2" : "=v"(ub[w])  : "v"(qa),      "v"(qb));
            asm("v_cvt_pk_bf16_f32 %0, %1, %2" : "=v"(uaa[w]) : "v"(pa * pa), "v"(pb * pb));
            asm("v_cvt_pk_bf16_f32 %0, %1, %2" : "=v"(ubb[w]) : "v"(qa * qa), "v"(qb * qb));
            asm("v_cvt_pk_bf16_f32 %0, %1, %2" : "=v"(uab[w]) : "v"(pa * qa), "v"(pb * qb));
        }
        bf16x8 fa  = __builtin_bit_cast(bf16x8, make_uint4(ua[0],  ua[1],  ua[2],  ua[3]));
        bf16x8 fb  = __builtin_bit_cast(bf16x8, make_uint4(ub[0],  ub[1],  ub[2],  ub[3]));
        bf16x8 faa = __builtin_bit_cast(bf16x8, make_uint4(uaa[0], uaa[1], uaa[2], uaa[3]));
        bf16x8 fbb = __builtin_bit_cast(bf16x8, make_uint4(ubb[0], ubb[1], ubb[2], ubb[3]));
        bf16x8 fab = __builtin_bit_cast(bf16x8, make_uint4(uab[0], uab[1], uab[2], uab[3]));

        f32x4 c0 = __builtin_amdgcn_mfma_f32_16x16x32_bf16(fa,  wB, z4, 0, 0, 0);
        f32x4 c1 = __builtin_amdgcn_mfma_f32_16x16x32_bf16(fb,  wB, z4, 0, 0, 0);
        f32x4 c2 = __builtin_amdgcn_mfma_f32_16x16x32_bf16(faa, wB, z4, 0, 0, 0);
        f32x4 c3 = __builtin_amdgcn_mfma_f32_16x16x32_bf16(fbb, wB, z4, 0, 0, 0);
        f32x4 c4 = __builtin_amdgcn_mfma_f32_16x16x32_bf16(fab, wB, z4, 0, 0, 0);

        int tx = 16 * n1 + lrow;
        int te = tx * 48 + rot48(16 * m1 + 4 * lgrp, tx);
        {
            unsigned lo, hi;
            asm("v_cvt_pk_bf16_f32 %0, %1, %2" : "=v"(lo) : "v"(c0[0]), "v"(c0[1]));
            asm("v_cvt_pk_bf16_f32 %0, %1, %2" : "=v"(hi) : "v"(c0[2]), "v"(c0[3]));
            *(uint2*)&T[0][te] = make_uint2(lo, hi);
            asm("v_cvt_pk_bf16_f32 %0, %1, %2" : "=v"(lo) : "v"(c1[0]), "v"(c1[1]));
            asm("v_cvt_pk_bf16_f32 %0, %1, %2" : "=v"(hi) : "v"(c1[2]), "v"(c1[3]));
            *(uint2*)&T[1][te] = make_uint2(lo, hi);
            asm("v_cvt_pk_bf16_f32 %0, %1, %2" : "=v"(lo) : "v"(c2[0]), "v"(c2[1]));
            asm("v_cvt_pk_bf16_f32 %0, %1, %2" : "=v"(hi) : "v"(c2[2]), "v"(c2[3]));
            *(uint2*)&T[2][te] = make_uint2(lo, hi);
            asm("v_cvt_pk_bf16_f32 %0, %1, %2" : "=v"(lo) : "v"(c3[0]), "v"(c3[1]));
            asm("v_cvt_pk_bf16_f32 %0, %1, %2" : "=v"(hi) : "v"(c3[2]), "v"(c3[3]));
            *(uint2*)&T[3][te] = make_uint2(lo, hi);
            asm("v_cvt_pk_bf16_f32 %0, %1, %2" : "=v"(lo) : "v"(c4[0]), "v"(c4[1]));
            asm("v_cvt_pk_bf16_f32 %0, %1, %2" : "=v"(hi) : "v"(c4[2]), "v"(c4[3]));
            *(uint2*)&T[4][te] = make_uint2(lo, hi);
        }
    }
    __syncthreads();

    // ---- pass 2: 8 positions (2 y-tiles x 4 x-tiles), MFMA(wA, T) + SSIM ----
    float lsum = 0.f;
    for (int p = wid; p < 8; p += 4) {
        int m2 = p >> 2;
        int n2 = wid;
        int tx = 16 * n2 + lrow;
        int te = tx * 48 + rot48(16 * m2 + 8 * lgrp, tx);
        f32x4 cf[5];
        #pragma unroll
        for (int f = 0; f < 5; ++f) {
            uint4 q = *(const uint4*)&T[f][te];
            cf[f] = __builtin_amdgcn_mfma_f32_16x16x32_bf16(wA, __builtin_bit_cast(bf16x8, q), z4, 0, 0, 0);
        }
        #pragma unroll
        for (int r = 0; r < 4; ++r) {
            float mu1 = cf[0][r], mu2 = cf[1][r];
            float m11 = mu1 * mu1, m22 = mu2 * mu2, m12 = mu1 * mu2;
            float s1 = cf[2][r] - m11;
            float s2 = cf[3][r] - m22;
            float s12 = cf[4][r] - m12;
            float num = (2.f * m12 + C1c) * (2.f * s12 + C2c);
            float den = (m11 + m22 + C1c) * (s1 + s2 + C2c);
            float v = num * __builtin_amdgcn_rcpf(den);
            lsum += fminf(fmaxf(v, 0.f), 1.f);
        }
    }

    // ---- block reduce ----
    #pragma unroll
    for (int off = 32; off > 0; off >>= 1) lsum += __shfl_down(lsum, off);
    if ((tid & 63) == 0) wred[wid] = lsum;
    __syncthreads();
    if (tid == 0) {
        float bsum = wred[0] + wred[1] + wred[2] + wred[3];
        int bid = (blockIdx.z * gridDim.y + blockIdx.y) * gridDim.x + blockIdx.x;
        if (ATOMIC) atomicAdd(&partials[0], bsum);
        else        partials[bid] = bsum;
    }
}

__global__ void ssim_finalize(const float* __restrict__ partials, int n,
                              float* __restrict__ out, float inv_npx)
{
    __shared__ float w[4];
    float s = 0.f;
    for (int i = threadIdx.x; i < n; i += 256) s += partials[i];
    #pragma unroll
    for (int off = 32; off > 0; off >>= 1) s += __shfl_down(s, off);
    if ((threadIdx.x & 63) == 0) w[threadIdx.x >> 6] = s;
    __syncthreads();
    if (threadIdx.x == 0) {
        float total = w[0] + w[1] + w[2] + w[3];
        float loss = 1.0f - total * inv_npx;
        out[0] = fmaxf(loss, 0.0f);
    }
}

extern "C" void kernel_launch(void* const* d_in, const int* in_sizes, int n_in,
                              void* d_out, int out_size, void* d_ws, size_t ws_size,
                              hipStream_t stream) {
    const float* img1   = (const float*)d_in[0];
    const float* img2   = (const float*)d_in[1];
    const float* window = (const float*)d_in[2];
    float* out      = (float*)d_out;
    float* partials = (float*)d_ws;

    int planes = in_sizes[0] >> 18;          // 48
    dim3 grid(512 / 64, 512 / 32, planes);   // 8 x 16 x 48 = 6144 blocks
    int npart = grid.x * grid.y * grid.z;
    float inv_npx = 1.0f / (float)in_sizes[0];

    if (ws_size >= (size_t)npart * sizeof(float)) {
        ssim_mfma2<false><<<grid, NT, 0, stream>>>(img1, img2, window, partials);
        ssim_finalize<<<1, 256, 0, stream>>>(partials, npart, out, inv_npx);
    } else {
        hipMemsetAsync(d_ws, 0, sizeof(float), stream);
        ssim_mfma2<true><<<grid, NT, 0, stream>>>(img1, img2, window, partials);
        ssim_finalize<<<1, 256, 0, stream>>>(partials, 1, out, inv_npx);
    }
}